// Round 11
// baseline (554.684 us; speedup 1.0000x reference)
//
#include <hip/hip_runtime.h>
#include <hip/hip_bf16.h>
#include <stdint.h>

#define BB 2
#define SS 2048
#define HQ 32
#define HKV 8
#define DD 128
#define WIN 512

typedef __bf16 bf16x8 __attribute__((ext_vector_type(8)));
typedef float f32x16 __attribute__((ext_vector_type(16)));

__device__ __forceinline__ bf16x8 cvt8(float4 a, float4 b, float s) {
  bf16x8 r;
  r[0] = (__bf16)(a.x * s); r[1] = (__bf16)(a.y * s);
  r[2] = (__bf16)(a.z * s); r[3] = (__bf16)(a.w * s);
  r[4] = (__bf16)(b.x * s); r[5] = (__bf16)(b.y * s);
  r[6] = (__bf16)(b.z * s); r[7] = (__bf16)(b.w * s);
  return r;
}

__device__ __forceinline__ uint32_t pk2(float lo, float hi) {
  uint32_t w;
  asm("v_cvt_pk_bf16_f32 %0, %1, %2" : "=v"(w) : "v"(lo), "v"(hi));
  return w;
}

// grid 256 blocks (1 per CU), block 1024 = 16 waves.
// Block: 128 q-rows x 4 heads of one (b,hkv).  Wave: 32 q-rows x 1 head.
// wave = (head = wave>>2, wq = wave&3).  KVBLK=64, 32x32x16 MFMA, P in registers.
__global__ __launch_bounds__(1024, 4) void attn_kernel(
    const float* __restrict__ qg, const float* __restrict__ kg,
    const float* __restrict__ vg, const float* __restrict__ sinkg,
    float* __restrict__ outg)
{
  const int col = (blockIdx.x & 7) + 8 * ((blockIdx.x >> 3) & 1);
  const int rank = blockIdx.x >> 4;                 // 0..15
  const int qtile = rank < 12 ? rank + 4 : 15 - rank; // longest-first
  const int hkv = col & 7, b = col >> 3;
  const int qb = qtile * 128;
  const int tid = threadIdx.x;
  const int wave = tid >> 6, lane = tid & 63;
  const int c5 = lane & 31, hi = lane >> 5;
  const int hq = (hkv << 2) + (wave >> 2);
  const int qw = qb + (wave & 3) * 32;
  const int qrow = qw + c5;

  __shared__ __align__(16) __bf16 Kl[2][64 * 128]; // [kv][d], 256B rows, swizzled
  __shared__ __align__(16) __bf16 Vt[2][128 * 64]; // [d][kv], 128B rows, swizzled

  const float LOG2E = 1.4426950408889634f;
  const float scale = 0.08838834764831845f * LOG2E;
  const float THR = 12.0f;

  // Q fragments: B-operand of S^T = K Q^T.  col=q=c5, k(d) = ch*16 + 8*hi + j
  bf16x8 qf[8];
  {
    const float* qp = qg + (((size_t)b * SS + qrow) * HQ + hq) * DD + hi * 8;
    #pragma unroll
    for (int ch = 0; ch < 8; ++ch) {
      float4 a = *(const float4*)(qp + ch * 16);
      float4 a2 = *(const float4*)(qp + ch * 16 + 4);
      qf[ch] = cvt8(a, a2, scale);
    }
  }
  const float sk = sinkg[hq] * LOG2E;

  float mm = -1e30f, ll = 0.f;
  f32x16 acc[4];
  #pragma unroll
  for (int d = 0; d < 4; ++d)
    #pragma unroll
    for (int r = 0; r < 16; ++r) acc[d][r] = 0.f;

  const int t0 = (qb > (WIN - 1) ? (qb - (WIN - 1)) : 0) >> 6;
  const int t1 = (qb + 127) >> 6;

  // staging roles: K: 64 rows x 16 chunks(8 floats); V: 128 d x 8 slots(8 kv)
  const int krow = tid >> 4, kchunk = tid & 15;
  const int vd = tid & 127, vslot = tid >> 7;
  const size_t KSTEP = (size_t)64 * HKV * DD;
  const float* kBase = kg + (((size_t)b * SS + krow) * HKV + hkv) * DD + kchunk * 8;
  const float* vBase = vg + (((size_t)b * SS + vslot * 8) * HKV + hkv) * DD + vd;

  float4 k0, k1; float vr[8];
  auto issue = [&](int t) {
    const float* kp = kBase + (size_t)t * KSTEP;
    k0 = *(const float4*)(kp); k1 = *(const float4*)(kp + 4);
    const float* vp = vBase + (size_t)t * KSTEP;
    #pragma unroll
    for (int j = 0; j < 8; ++j) vr[j] = vp[(size_t)j * (HKV * DD)];
  };
  const int ksw = ((krow ^ (krow >> 3)) & 7) << 4;
  const int vsw = ((vd ^ (vd >> 3)) & 7) << 4;
  auto commit = [&](int buf) {
    *(bf16x8*)((char*)(&Kl[buf][0]) + krow * 256 + ((kchunk * 16) ^ ksw)) =
        cvt8(k0, k1, 1.f);
    bf16x8 w;
    #pragma unroll
    for (int j = 0; j < 8; ++j) w[j] = (__bf16)vr[j];
    *(bf16x8*)((char*)(&Vt[buf][0]) + vd * 128 + ((vslot * 16) ^ vsw)) = w;
  };

  issue(t0);
  commit(0);
  __syncthreads();
  int cur = 0;

  // per-lane read swizzles
  const int swA = ((c5 ^ (c5 >> 3)) & 7) << 4;  // K row c5
  const int swB = swA ^ 0x40;                   // K row 32+c5

  for (int t = t0; t <= t1; ++t) {
    if (t < t1) issue(t + 1);
    const int kb = t << 6;

    // wave-level dead-tile guard (keep barrier below outside)
    if (kb <= qw + 31 && kb + 63 >= qw - (WIN - 1)) {
      const char* Ksc = (const char*)&Kl[cur][0];
      const char* Vsc = (const char*)&Vt[cur][0];

      // ---- QK^T: S^T[64 kv][32 q], two 32-kv halves ----
      f32x16 s0, s1;
      #pragma unroll
      for (int r = 0; r < 16; ++r) { s0[r] = 0.f; s1[r] = 0.f; }
      __builtin_amdgcn_s_setprio(1);
      #pragma unroll
      for (int ch = 0; ch < 8; ++ch) {
        const int colb = ch * 32 + hi * 16;
        bf16x8 a0 = *(const bf16x8*)(Ksc + c5 * 256 + (colb ^ swA));
        bf16x8 a1 = *(const bf16x8*)(Ksc + (32 + c5) * 256 + (colb ^ swB));
        s0 = __builtin_amdgcn_mfma_f32_32x32x16_bf16(a0, qf[ch], s0, 0, 0, 0);
        s1 = __builtin_amdgcn_mfma_f32_32x32x16_bf16(a1, qf[ch], s1, 0, 0, 0);
      }
      __builtin_amdgcn_s_setprio(0);

      const bool noMask = (kb + 63 <= qw) && (kb >= qw - (WIN - 32));

      if (!noMask) {
        #pragma unroll
        for (int r = 0; r < 16; ++r) {
          const int lr = (r & 3) + 8 * (r >> 2) + 4 * hi;
          const int kv0 = kb + lr, kv1 = kv0 + 32;
          const bool ok0 = (kv0 <= qrow) && (qrow - kv0 < WIN);
          const bool ok1 = (kv1 <= qrow) && (qrow - kv1 < WIN);
          s0[r] = ok0 ? s0[r] : -1e30f;
          s1[r] = ok1 ? s1[r] : -1e30f;
        }
      }
      float tmax = s0[0];
      #pragma unroll
      for (int r = 1; r < 16; ++r) tmax = fmaxf(tmax, s0[r]);
      #pragma unroll
      for (int r = 0; r < 16; ++r) tmax = fmaxf(tmax, s1[r]);
      tmax = fmaxf(tmax, __shfl_xor(tmax, 32));

      const bool resc = __any(tmax > mm + THR);
      const float mnew = resc ? fmaxf(mm, tmax) : mm;
      float tsum = 0.f;
      if (noMask) {
        #pragma unroll
        for (int r = 0; r < 16; ++r) {
          s0[r] = exp2f(s0[r] - mnew); tsum += s0[r];
          s1[r] = exp2f(s1[r] - mnew); tsum += s1[r];
        }
      } else {
        #pragma unroll
        for (int r = 0; r < 16; ++r) {
          s0[r] = (s0[r] > -9e29f) ? exp2f(s0[r] - mnew) : 0.f; tsum += s0[r];
          s1[r] = (s1[r] > -9e29f) ? exp2f(s1[r] - mnew) : 0.f; tsum += s1[r];
        }
      }
      tsum += __shfl_xor(tsum, 32);

      if (resc) {
        const float scl = exp2f(mm - mnew);
        ll = ll * scl + tsum;
        #pragma unroll
        for (int d = 0; d < 4; ++d)
          #pragma unroll
          for (int r = 0; r < 16; ++r) acc[d][r] *= scl;
        mm = mnew;
      } else {
        ll += tsum;
      }

      // ---- P^T B-frags in-register: lane<->lane^32 exchange per 16-kv quarter ----
      bf16x8 pb[4];
      #pragma unroll
      for (int kvq = 0; kvq < 4; ++kvq) {
        const int bq = (kvq & 1) * 8;
        float e0, e1, e2, e3, e4, e5, e6, e7;
        if (kvq & 2) {
          e0 = s1[bq+0]; e1 = s1[bq+1]; e2 = s1[bq+2]; e3 = s1[bq+3];
          e4 = s1[bq+4]; e5 = s1[bq+5]; e6 = s1[bq+6]; e7 = s1[bq+7];
        } else {
          e0 = s0[bq+0]; e1 = s0[bq+1]; e2 = s0[bq+2]; e3 = s0[bq+3];
          e4 = s0[bq+4]; e5 = s0[bq+5]; e6 = s0[bq+6]; e7 = s0[bq+7];
        }
        const uint32_t A0 = pk2(e0, e1), A1 = pk2(e2, e3);
        const uint32_t B0 = pk2(e4, e5), B1 = pk2(e6, e7);
        const uint32_t XA0 = __shfl_xor(A0, 32), XA1 = __shfl_xor(A1, 32);
        const uint32_t XB0 = __shfl_xor(B0, 32), XB1 = __shfl_xor(B1, 32);
        union { uint4 u; bf16x8 v; } cvu;
        cvu.u.x = hi ? XB0 : A0;
        cvu.u.y = hi ? XB1 : A1;
        cvu.u.z = hi ? B0 : XA0;
        cvu.u.w = hi ? B1 : XA1;
        pb[kvq] = cvu.v;
      }

      // ---- PV: O^T[d][q] = V^T P^T ----
      __builtin_amdgcn_s_setprio(1);
      #pragma unroll
      for (int d = 0; d < 4; ++d) {
        const int rowb = (d * 32 + c5) * 128;
        const int swV = swA ^ ((d & 1) << 6);
        #pragma unroll
        for (int kvq = 0; kvq < 4; ++kvq) {
          bf16x8 va = *(const bf16x8*)(Vsc + rowb + ((kvq * 32 + hi * 16) ^ swV));
          acc[d] = __builtin_amdgcn_mfma_f32_32x32x16_bf16(va, pb[kvq], acc[d], 0, 0, 0);
        }
      }
      __builtin_amdgcn_s_setprio(0);
    }

    if (t < t1) {
      commit(cur ^ 1);
      __syncthreads();
      cur ^= 1;
    }
  }

  // ---- epilogue: sink + normalize (lane-local), float4 stores ----
  {
    const float Mf = fmaxf(mm, sk);
    const float ex = exp2f(mm - Mf);
    const float denom = ll * ex + exp2f(sk - Mf);
    const float fac = ex / denom;
    float* orow = outg + (((size_t)b * SS + qrow) * HQ + hq) * DD;
    #pragma unroll
    for (int d = 0; d < 4; ++d) {
      #pragma unroll
      for (int q4 = 0; q4 < 4; ++q4) {
        float4 o;
        o.x = acc[d][q4 * 4 + 0] * fac;
        o.y = acc[d][q4 * 4 + 1] * fac;
        o.z = acc[d][q4 * 4 + 2] * fac;
        o.w = acc[d][q4 * 4 + 3] * fac;
        *(float4*)(orow + d * 32 + q4 * 8 + 4 * hi) = o;
      }
    }
  }
}

// ---- cache path: inverse-map single-pass fill ----
__global__ void build_inv(const int* __restrict__ ids, int* __restrict__ inv,
                          int npages, int nslots) {
  const int i = threadIdx.x;
  if (i < npages) inv[i] = -1;
  __syncthreads();
  if (i < nslots) inv[ids[i]] = i;
}

__global__ void page_fill(const float* __restrict__ kg, const float* __restrict__ vg,
                          const float* __restrict__ cache_in, const int* __restrict__ inv,
                          float* __restrict__ cache) {
  const int page = blockIdx.x, half = blockIdx.y;
  const int slot = inv[page];
  float4* d4 = (float4*)cache;
  const size_t dbase = (((size_t)page * 2 + half) * 8) * 1024;
  if (slot >= 0) {
    const int b = slot >> 6, blk = slot & 63;
    const float4* s4 = (const float4*)(half ? vg : kg);
    for (int f = threadIdx.x; f < 8192; f += blockDim.x) {
      const int d = f & 31, s = (f >> 5) & 31, h = f >> 10;
      d4[dbase + (size_t)h * 1024 + s * 32 + d] =
          s4[(((size_t)b * SS + blk * 32 + s) * 8 + h) * 32 + d];
    }
  } else {
    const float4* s4 = (const float4*)cache_in;
    for (int f = threadIdx.x; f < 8192; f += blockDim.x)
      d4[dbase + f] = s4[dbase + f];
  }
}

// fallback (no workspace): copy + scatter
__global__ void cache_copy(const float* __restrict__ src, float* __restrict__ dst, int n4) {
  const float4* s = (const float4*)src;
  float4* d = (float4*)dst;
  for (int i = blockIdx.x * blockDim.x + threadIdx.x; i < n4; i += gridDim.x * blockDim.x)
    d[i] = s[i];
}
__global__ void cache_scatter(const float* __restrict__ kg, const float* __restrict__ vg,
                              const int* __restrict__ ids, float* __restrict__ cache) {
  const int slot = blockIdx.x;
  const int half = blockIdx.y;
  const int b = slot >> 6, blk = slot & 63;
  const int page = ids[slot];
  const float4* s4 = (const float4*)(half ? vg : kg);
  float4* d4 = (float4*)cache;
  for (int f = threadIdx.x; f < 8192; f += blockDim.x) {
    const int d = f & 31, s = (f >> 5) & 31, h = f >> 10;
    d4[(((size_t)page * 2 + half) * 8 + h) * 1024 + s * 32 + d] =
        s4[(((size_t)b * SS + blk * 32 + s) * 8 + h) * 32 + d];
  }
}

extern "C" void kernel_launch(void* const* d_in, const int* in_sizes, int n_in,
                              void* d_out, int out_size, void* d_ws, size_t ws_size,
                              hipStream_t stream) {
  const float* q = (const float*)d_in[0];
  const float* k = (const float*)d_in[1];
  const float* v = (const float*)d_in[2];
  const float* cache_in = (const float*)d_in[3];
  const int* ids = (const int*)d_in[4];
  const float* sink = (const float*)d_in[5];
  float* out = (float*)d_out;
  float* cache_out = out + (size_t)BB * SS * HQ * DD; // 16,777,216

  const int nslots = in_sizes[4];                       // B * nb = 128
  const int npages = in_sizes[3] / (2 * HKV * 32 * DD); // 128

  if (ws_size >= (size_t)npages * sizeof(int) && npages <= 1024) {
    int* inv = (int*)d_ws;
    build_inv<<<1, 1024, 0, stream>>>(ids, inv, npages, nslots);
    page_fill<<<dim3(npages, 2), 256, 0, stream>>>(k, v, cache_in, inv, cache_out);
  } else {
    cache_copy<<<4096, 256, 0, stream>>>(cache_in, cache_out, (BB * SS * HKV * DD * 2) / 4);
    cache_scatter<<<dim3(BB * 64, 2), 256, 0, stream>>>(k, v, ids, cache_out);
  }
  attn_kernel<<<256, 1024, 0, stream>>>(q, k, v, sink, out);
}

// Round 12
// 107.800 us; speedup vs baseline: 5.1455x; 5.1455x over previous
//
#include <hip/hip_runtime.h>
#include <hip/hip_bf16.h>
#include <stdint.h>

#define BB 2
#define SS 2048
#define HQ 32
#define HKV 8
#define DD 128
#define WIN 512

typedef __bf16 bf16x8 __attribute__((ext_vector_type(8)));
typedef float f32x16 __attribute__((ext_vector_type(16)));

__device__ __forceinline__ bf16x8 cvt8(float4 a, float4 b, float s) {
  bf16x8 r;
  r[0] = (__bf16)(a.x * s); r[1] = (__bf16)(a.y * s);
  r[2] = (__bf16)(a.z * s); r[3] = (__bf16)(a.w * s);
  r[4] = (__bf16)(b.x * s); r[5] = (__bf16)(b.y * s);
  r[6] = (__bf16)(b.z * s); r[7] = (__bf16)(b.w * s);
  return r;
}

__device__ __forceinline__ uint32_t pk2(float lo, float hi) {
  uint32_t w;
  asm("v_cvt_pk_bf16_f32 %0, %1, %2" : "=v"(w) : "v"(lo), "v"(hi));
  return w;
}

__device__ __forceinline__ unsigned short bfu(float x) {
  union { __bf16 b; unsigned short u; } c; c.b = (__bf16)x; return c.u;
}

#define SWZ(r) ((((r) ^ ((r) >> 3)) & 7) << 4)

// ============ main attention: bf16-prepped K/V, vector-only staging ============
// grid 512, block 512 = 8 waves. wave = 32q x 1 head. KVBLK=64, 32x32x16 MFMA.
__global__ __launch_bounds__(512, 2) void attn_kernel(
    const float* __restrict__ qg, const float* __restrict__ sinkg,
    float* __restrict__ outg,
    const unsigned short* __restrict__ kbg, const unsigned short* __restrict__ vtg)
{
  const int col = (blockIdx.x & 7) + 8 * ((blockIdx.x >> 3) & 1);
  const int rank = blockIdx.x >> 4;
  const int qtile = rank < 24 ? rank + 8 : 31 - rank;  // longest-first
  const int hkv = col & 7, b = col >> 3;
  const int qb = qtile * 64;
  const int tid = threadIdx.x;
  const int wave = tid >> 6, lane = tid & 63;
  const int c5 = lane & 31, hi = lane >> 5;
  const int hq = (hkv << 2) + (wave >> 1);
  const int qw = qb + (wave & 1) * 32;
  const int qrow = qw + c5;

  __shared__ __align__(16) __bf16 Kl[2][64 * 128]; // [kv][d], 256B rows, swizzled
  __shared__ __align__(16) __bf16 Vt[2][128 * 64]; // [d][kv], 128B rows, swizzled

  const float LOG2E = 1.4426950408889634f;
  const float scale = 0.08838834764831845f * LOG2E;
  const float THR = 12.0f;

  bf16x8 qf[8];
  {
    const float* qp = qg + (((size_t)b * SS + qrow) * HQ + hq) * DD + hi * 8;
    #pragma unroll
    for (int ch = 0; ch < 8; ++ch) {
      float4 a = *(const float4*)(qp + ch * 16);
      float4 a2 = *(const float4*)(qp + ch * 16 + 4);
      qf[ch] = cvt8(a, a2, scale);
    }
  }
  const float sk = sinkg[hq] * LOG2E;

  float mm = -1e30f, ll = 0.f;
  f32x16 acc[4];
  #pragma unroll
  for (int d = 0; d < 4; ++d)
    #pragma unroll
    for (int r = 0; r < 16; ++r) acc[d][r] = 0.f;

  const int t0 = (qb > (WIN - 1) ? (qb - (WIN - 1)) : 0) >> 6;
  const int t1 = (qb + 63) >> 6;

  // bf16 tile bases: 16KB per 64-kv tile, contiguous
  const char* kcol = (const char*)kbg + (size_t)(b * HKV + hkv) * (SS * DD * 2);
  const char* vcol = (const char*)vtg + (size_t)(b * HKV + hkv) * (SS * DD * 2);
  const int p0 = tid * 32;
  const int kr = p0 >> 8, kx = p0 & 255;
  const int vrw = p0 >> 7, vx = p0 & 127;
  const int kd0 = kr * 256 + (kx ^ SWZ(kr)), kd1 = kr * 256 + ((kx + 16) ^ SWZ(kr));
  const int vd0 = vrw * 128 + (vx ^ SWZ(vrw)), vd1 = vrw * 128 + ((vx + 16) ^ SWZ(vrw));

  uint4 ksA, ksB, vsA, vsB;
  auto issue = [&](int t) {
    const char* kt = kcol + (size_t)t * 16384;
    const char* vt = vcol + (size_t)t * 16384;
    ksA = *(const uint4*)(kt + p0); ksB = *(const uint4*)(kt + p0 + 16);
    vsA = *(const uint4*)(vt + p0); vsB = *(const uint4*)(vt + p0 + 16);
  };
  auto commit = [&](int buf) {
    char* kb_ = (char*)&Kl[buf][0]; char* vb_ = (char*)&Vt[buf][0];
    *(uint4*)(kb_ + kd0) = ksA; *(uint4*)(kb_ + kd1) = ksB;
    *(uint4*)(vb_ + vd0) = vsA; *(uint4*)(vb_ + vd1) = vsB;
  };

  issue(t0);
  commit(0);
  __syncthreads();
  int cur = 0;

  const int swA = SWZ(c5);        // K row c5
  const int swB = swA ^ 0x40;     // K row 32+c5

  for (int t = t0; t <= t1; ++t) {
    if (t < t1) issue(t + 1);
    const int kb = t << 6;

    if (kb <= qw + 31 && kb + 63 >= qw - (WIN - 1)) {
      const char* Ksc = (const char*)&Kl[cur][0];
      const char* Vsc = (const char*)&Vt[cur][0];

      // ---- QK^T: S^T[64 kv][32 q], two 32-kv halves ----
      f32x16 s0, s1;
      #pragma unroll
      for (int r = 0; r < 16; ++r) { s0[r] = 0.f; s1[r] = 0.f; }
      __builtin_amdgcn_s_setprio(1);
      #pragma unroll
      for (int ch = 0; ch < 8; ++ch) {
        const int colb = ch * 32 + hi * 16;
        bf16x8 a0 = *(const bf16x8*)(Ksc + c5 * 256 + (colb ^ swA));
        bf16x8 a1 = *(const bf16x8*)(Ksc + (32 + c5) * 256 + (colb ^ swB));
        s0 = __builtin_amdgcn_mfma_f32_32x32x16_bf16(a0, qf[ch], s0, 0, 0, 0);
        s1 = __builtin_amdgcn_mfma_f32_32x32x16_bf16(a1, qf[ch], s1, 0, 0, 0);
      }
      __builtin_amdgcn_s_setprio(0);

      const bool noMask = (kb + 63 <= qw) && (kb >= qw - (WIN - 32));

      if (!noMask) {
        #pragma unroll
        for (int r = 0; r < 16; ++r) {
          const int lr = (r & 3) + 8 * (r >> 2) + 4 * hi;
          const int kv0 = kb + lr, kv1 = kv0 + 32;
          const bool ok0 = (kv0 <= qrow) && (qrow - kv0 < WIN);
          const bool ok1 = (kv1 <= qrow) && (qrow - kv1 < WIN);
          s0[r] = ok0 ? s0[r] : -1e30f;
          s1[r] = ok1 ? s1[r] : -1e30f;
        }
      }
      float tmax = s0[0];
      #pragma unroll
      for (int r = 1; r < 16; ++r) tmax = fmaxf(tmax, s0[r]);
      #pragma unroll
      for (int r = 0; r < 16; ++r) tmax = fmaxf(tmax, s1[r]);
      tmax = fmaxf(tmax, __shfl_xor(tmax, 32));

      const bool resc = __any(tmax > mm + THR);
      const float mnew = resc ? fmaxf(mm, tmax) : mm;
      float tsum = 0.f;
      if (noMask) {
        #pragma unroll
        for (int r = 0; r < 16; ++r) {
          s0[r] = exp2f(s0[r] - mnew); tsum += s0[r];
          s1[r] = exp2f(s1[r] - mnew); tsum += s1[r];
        }
      } else {
        #pragma unroll
        for (int r = 0; r < 16; ++r) {
          s0[r] = (s0[r] > -9e29f) ? exp2f(s0[r] - mnew) : 0.f; tsum += s0[r];
          s1[r] = (s1[r] > -9e29f) ? exp2f(s1[r] - mnew) : 0.f; tsum += s1[r];
        }
      }
      tsum += __shfl_xor(tsum, 32);

      if (resc) {
        const float scl = exp2f(mm - mnew);
        ll = ll * scl + tsum;
        #pragma unroll
        for (int d = 0; d < 4; ++d)
          #pragma unroll
          for (int r = 0; r < 16; ++r) acc[d][r] *= scl;
        mm = mnew;
      } else {
        ll += tsum;
      }

      // ---- P^T B-frags in-register: lane<->lane^32 exchange ----
      bf16x8 pb[4];
      #pragma unroll
      for (int kvq = 0; kvq < 4; ++kvq) {
        const int bq = (kvq & 1) * 8;
        float e0, e1, e2, e3, e4, e5, e6, e7;
        if (kvq & 2) {
          e0 = s1[bq+0]; e1 = s1[bq+1]; e2 = s1[bq+2]; e3 = s1[bq+3];
          e4 = s1[bq+4]; e5 = s1[bq+5]; e6 = s1[bq+6]; e7 = s1[bq+7];
        } else {
          e0 = s0[bq+0]; e1 = s0[bq+1]; e2 = s0[bq+2]; e3 = s0[bq+3];
          e4 = s0[bq+4]; e5 = s0[bq+5]; e6 = s0[bq+6]; e7 = s0[bq+7];
        }
        const uint32_t A0 = pk2(e0, e1), A1 = pk2(e2, e3);
        const uint32_t B0 = pk2(e4, e5), B1 = pk2(e6, e7);
        const uint32_t XA0 = __shfl_xor(A0, 32), XA1 = __shfl_xor(A1, 32);
        const uint32_t XB0 = __shfl_xor(B0, 32), XB1 = __shfl_xor(B1, 32);
        union { uint4 u; bf16x8 v; } cvu;
        cvu.u.x = hi ? XB0 : A0;
        cvu.u.y = hi ? XB1 : A1;
        cvu.u.z = hi ? B0 : XA0;
        cvu.u.w = hi ? B1 : XA1;
        pb[kvq] = cvu.v;
      }

      // ---- PV: O^T[d][q] = V^T P^T ----
      __builtin_amdgcn_s_setprio(1);
      #pragma unroll
      for (int d = 0; d < 4; ++d) {
        const int rowb = (d * 32 + c5) * 128;
        const int swV = swA ^ ((d & 1) << 6);
        #pragma unroll
        for (int kvq = 0; kvq < 4; ++kvq) {
          bf16x8 va = *(const bf16x8*)(Vsc + rowb + ((kvq * 32 + hi * 16) ^ swV));
          acc[d] = __builtin_amdgcn_mfma_f32_32x32x16_bf16(va, pb[kvq], acc[d], 0, 0, 0);
        }
      }
      __builtin_amdgcn_s_setprio(0);
    }

    if (t < t1) {
      commit(cur ^ 1);
      __syncthreads();
      cur ^= 1;
    }
  }

  // ---- epilogue ----
  {
    const float Mf = fmaxf(mm, sk);
    const float ex = exp2f(mm - Mf);
    const float denom = ll * ex + exp2f(sk - Mf);
    const float fac = ex / denom;
    float* orow = outg + (((size_t)b * SS + qrow) * HQ + hq) * DD;
    #pragma unroll
    for (int d = 0; d < 4; ++d) {
      #pragma unroll
      for (int q4 = 0; q4 < 4; ++q4) {
        float4 o;
        o.x = acc[d][q4 * 4 + 0] * fac;
        o.y = acc[d][q4 * 4 + 1] * fac;
        o.z = acc[d][q4 * 4 + 2] * fac;
        o.w = acc[d][q4 * 4 + 3] * fac;
        *(float4*)(orow + d * 32 + q4 * 8 + 4 * hi) = o;
      }
    }
  }
}

// ============ prep: fp32 K/V -> bf16 Kb[col][s][d], Vt[col][tile][d][kv] ============
// grid (BB*HKV*32, 2), 256 threads
__global__ void prep_kv(const float* __restrict__ kg, const float* __restrict__ vg,
                        unsigned short* __restrict__ kb, unsigned short* __restrict__ vt) {
  const int bx = blockIdx.x;
  const int t = bx & 31, colx = bx >> 5;
  const int b = colx >> 3, hkv = colx & 7;
  const int kbrow = t * 64;
  if (blockIdx.y == 0) {
    #pragma unroll
    for (int i = 0; i < 8; ++i) {
      const int idx = i * 1024 + threadIdx.x * 4;
      const int r = idx >> 7, d = idx & 127;
      float4 v = *(const float4*)(kg + (((size_t)b * SS + kbrow + r) * HKV + hkv) * DD + d);
      ushort4 o = make_ushort4(bfu(v.x), bfu(v.y), bfu(v.z), bfu(v.w));
      *(ushort4*)(kb + ((size_t)colx * SS + kbrow + r) * DD + d) = o;
    }
  } else {
    __shared__ unsigned short Vl[64][132];
    #pragma unroll
    for (int i = 0; i < 8; ++i) {
      const int idx = i * 1024 + threadIdx.x * 4;
      const int kv = idx >> 7, d = idx & 127;
      float4 v = *(const float4*)(vg + (((size_t)b * SS + kbrow + kv) * HKV + hkv) * DD + d);
      Vl[kv][d + 0] = bfu(v.x); Vl[kv][d + 1] = bfu(v.y);
      Vl[kv][d + 2] = bfu(v.z); Vl[kv][d + 3] = bfu(v.w);
    }
    __syncthreads();
    #pragma unroll
    for (int i = 0; i < 8; ++i) {
      const int idx = i * 1024 + threadIdx.x * 4;
      const int d = idx >> 6, kv = idx & 63;
      ushort4 o = make_ushort4(Vl[kv + 0][d], Vl[kv + 1][d], Vl[kv + 2][d], Vl[kv + 3][d]);
      *(ushort4*)(vt + ((size_t)colx * 32 + t) * 8192 + d * 64 + kv) = o;
    }
  }
}

// ============ fallback attention (R10, fp32 staging) ============
__global__ __launch_bounds__(512, 2) void attn_fallback(
    const float* __restrict__ qg, const float* __restrict__ kg,
    const float* __restrict__ vg, const float* __restrict__ sinkg,
    float* __restrict__ outg)
{
  const int col = (blockIdx.x & 7) + 8 * ((blockIdx.x >> 3) & 1);
  const int rank = blockIdx.x >> 4;
  const int qtile = rank < 24 ? rank + 8 : 31 - rank;
  const int hkv = col & 7, b = col >> 3;
  const int qb = qtile * 64;
  const int tid = threadIdx.x;
  const int wave = tid >> 6, lane = tid & 63;
  const int c5 = lane & 31, hi = lane >> 5;
  const int hq = (hkv << 2) + (wave >> 1);
  const int qw = qb + (wave & 1) * 32;
  const int qrow = qw + c5;

  __shared__ __align__(16) __bf16 Kl[2][64 * 128];
  __shared__ __align__(16) __bf16 Vt[2][128 * 64];

  const float LOG2E = 1.4426950408889634f;
  const float scale = 0.08838834764831845f * LOG2E;
  const float THR = 12.0f;

  bf16x8 qf[8];
  {
    const float* qp = qg + (((size_t)b * SS + qrow) * HQ + hq) * DD + hi * 8;
    #pragma unroll
    for (int ch = 0; ch < 8; ++ch) {
      float4 a = *(const float4*)(qp + ch * 16);
      float4 a2 = *(const float4*)(qp + ch * 16 + 4);
      qf[ch] = cvt8(a, a2, scale);
    }
  }
  const float sk = sinkg[hq] * LOG2E;

  float mm = -1e30f, ll = 0.f;
  f32x16 acc[4];
  #pragma unroll
  for (int d = 0; d < 4; ++d)
    #pragma unroll
    for (int r = 0; r < 16; ++r) acc[d][r] = 0.f;

  const int t0 = (qb > (WIN - 1) ? (qb - (WIN - 1)) : 0) >> 6;
  const int t1 = (qb + 63) >> 6;

  const int krow = tid >> 3, kchunk = tid & 7;
  const int vd = tid & 127, vslot = tid >> 7;
  const size_t KSTEP = (size_t)64 * HKV * DD;
  const float* kBase = kg + (((size_t)b * SS + krow) * HKV + hkv) * DD + kchunk * 16;
  const float* vBase = vg + (((size_t)b * SS + vslot * 16) * HKV + hkv) * DD + vd;

  float4 k0, k1, k2, k3; float vr[16];
  auto issue = [&](int t) {
    const float* kp = kBase + (size_t)t * KSTEP;
    k0 = *(const float4*)(kp);     k1 = *(const float4*)(kp + 4);
    k2 = *(const float4*)(kp + 8); k3 = *(const float4*)(kp + 12);
    const float* vp = vBase + (size_t)t * KSTEP;
    #pragma unroll
    for (int j = 0; j < 16; ++j) vr[j] = vp[(size_t)j * (HKV * DD)];
  };
  const int ksw = SWZ(krow);
  const int vsw = SWZ(vd);
  auto commit = [&](int buf) {
    char* kd = (char*)(&Kl[buf][0]) + krow * 256;
    *(bf16x8*)(kd + ((kchunk * 32) ^ ksw)) = cvt8(k0, k1, 1.f);
    *(bf16x8*)(kd + ((kchunk * 32 + 16) ^ ksw)) = cvt8(k2, k3, 1.f);
    char* vdst = (char*)(&Vt[buf][0]) + vd * 128;
    bf16x8 w0, w1;
    #pragma unroll
    for (int j = 0; j < 8; ++j) { w0[j] = (__bf16)vr[j]; w1[j] = (__bf16)vr[8 + j]; }
    *(bf16x8*)(vdst + ((vslot * 32) ^ vsw)) = w0;
    *(bf16x8*)(vdst + ((vslot * 32 + 16) ^ vsw)) = w1;
  };

  issue(t0);
  commit(0);
  __syncthreads();
  int cur = 0;

  const int swA = SWZ(c5);
  const int swB = swA ^ 0x40;

  for (int t = t0; t <= t1; ++t) {
    if (t < t1) issue(t + 1);
    const int kb = t << 6;
    if (kb <= qw + 31 && kb + 63 >= qw - (WIN - 1)) {
      const char* Ksc = (const char*)&Kl[cur][0];
      const char* Vsc = (const char*)&Vt[cur][0];
      f32x16 s0, s1;
      #pragma unroll
      for (int r = 0; r < 16; ++r) { s0[r] = 0.f; s1[r] = 0.f; }
      __builtin_amdgcn_s_setprio(1);
      #pragma unroll
      for (int ch = 0; ch < 8; ++ch) {
        const int colb = ch * 32 + hi * 16;
        bf16x8 a0 = *(const bf16x8*)(Ksc + c5 * 256 + (colb ^ swA));
        bf16x8 a1 = *(const bf16x8*)(Ksc + (32 + c5) * 256 + (colb ^ swB));
        s0 = __builtin_amdgcn_mfma_f32_32x32x16_bf16(a0, qf[ch], s0, 0, 0, 0);
        s1 = __builtin_amdgcn_mfma_f32_32x32x16_bf16(a1, qf[ch], s1, 0, 0, 0);
      }
      __builtin_amdgcn_s_setprio(0);

      const bool noMask = (kb + 63 <= qw) && (kb >= qw - (WIN - 32));
      if (!noMask) {
        #pragma unroll
        for (int r = 0; r < 16; ++r) {
          const int lr = (r & 3) + 8 * (r >> 2) + 4 * hi;
          const int kv0 = kb + lr, kv1 = kv0 + 32;
          const bool ok0 = (kv0 <= qrow) && (qrow - kv0 < WIN);
          const bool ok1 = (kv1 <= qrow) && (qrow - kv1 < WIN);
          s0[r] = ok0 ? s0[r] : -1e30f;
          s1[r] = ok1 ? s1[r] : -1e30f;
        }
      }
      float tmax = s0[0];
      #pragma unroll
      for (int r = 1; r < 16; ++r) tmax = fmaxf(tmax, s0[r]);
      #pragma unroll
      for (int r = 0; r < 16; ++r) tmax = fmaxf(tmax, s1[r]);
      tmax = fmaxf(tmax, __shfl_xor(tmax, 32));
      const bool resc = __any(tmax > mm + THR);
      const float mnew = resc ? fmaxf(mm, tmax) : mm;
      float tsum = 0.f;
      if (noMask) {
        #pragma unroll
        for (int r = 0; r < 16; ++r) {
          s0[r] = exp2f(s0[r] - mnew); tsum += s0[r];
          s1[r] = exp2f(s1[r] - mnew); tsum += s1[r];
        }
      } else {
        #pragma unroll
        for (int r = 0; r < 16; ++r) {
          s0[r] = (s0[r] > -9e29f) ? exp2f(s0[r] - mnew) : 0.f; tsum += s0[r];
          s1[r] = (s1[r] > -9e29f) ? exp2f(s1[r] - mnew) : 0.f; tsum += s1[r];
        }
      }
      tsum += __shfl_xor(tsum, 32);
      if (resc) {
        const float scl = exp2f(mm - mnew);
        ll = ll * scl + tsum;
        #pragma unroll
        for (int d = 0; d < 4; ++d)
          #pragma unroll
          for (int r = 0; r < 16; ++r) acc[d][r] *= scl;
        mm = mnew;
      } else {
        ll += tsum;
      }
      bf16x8 pb[4];
      #pragma unroll
      for (int kvq = 0; kvq < 4; ++kvq) {
        const int bq = (kvq & 1) * 8;
        float e0, e1, e2, e3, e4, e5, e6, e7;
        if (kvq & 2) {
          e0 = s1[bq+0]; e1 = s1[bq+1]; e2 = s1[bq+2]; e3 = s1[bq+3];
          e4 = s1[bq+4]; e5 = s1[bq+5]; e6 = s1[bq+6]; e7 = s1[bq+7];
        } else {
          e0 = s0[bq+0]; e1 = s0[bq+1]; e2 = s0[bq+2]; e3 = s0[bq+3];
          e4 = s0[bq+4]; e5 = s0[bq+5]; e6 = s0[bq+6]; e7 = s0[bq+7];
        }
        const uint32_t A0 = pk2(e0, e1), A1 = pk2(e2, e3);
        const uint32_t B0 = pk2(e4, e5), B1 = pk2(e6, e7);
        const uint32_t XA0 = __shfl_xor(A0, 32), XA1 = __shfl_xor(A1, 32);
        const uint32_t XB0 = __shfl_xor(B0, 32), XB1 = __shfl_xor(B1, 32);
        union { uint4 u; bf16x8 v; } cvu;
        cvu.u.x = hi ? XB0 : A0;
        cvu.u.y = hi ? XB1 : A1;
        cvu.u.z = hi ? B0 : XA0;
        cvu.u.w = hi ? B1 : XA1;
        pb[kvq] = cvu.v;
      }
      __builtin_amdgcn_s_setprio(1);
      #pragma unroll
      for (int d = 0; d < 4; ++d) {
        const int rowb = (d * 32 + c5) * 128;
        const int swV = swA ^ ((d & 1) << 6);
        #pragma unroll
        for (int kvq = 0; kvq < 4; ++kvq) {
          bf16x8 va = *(const bf16x8*)(Vsc + rowb + ((kvq * 32 + hi * 16) ^ swV));
          acc[d] = __builtin_amdgcn_mfma_f32_32x32x16_bf16(va, pb[kvq], acc[d], 0, 0, 0);
        }
      }
      __builtin_amdgcn_s_setprio(0);
    }
    if (t < t1) {
      commit(cur ^ 1);
      __syncthreads();
      cur ^= 1;
    }
  }
  {
    const float Mf = fmaxf(mm, sk);
    const float ex = exp2f(mm - Mf);
    const float denom = ll * ex + exp2f(sk - Mf);
    const float fac = ex / denom;
    float* orow = outg + (((size_t)b * SS + qrow) * HQ + hq) * DD;
    #pragma unroll
    for (int d = 0; d < 4; ++d) {
      #pragma unroll
      for (int q4 = 0; q4 < 4; ++q4) {
        float4 o;
        o.x = acc[d][q4 * 4 + 0] * fac;
        o.y = acc[d][q4 * 4 + 1] * fac;
        o.z = acc[d][q4 * 4 + 2] * fac;
        o.w = acc[d][q4 * 4 + 3] * fac;
        *(float4*)(orow + d * 32 + q4 * 8 + 4 * hi) = o;
      }
    }
  }
}

// ---- cache path ----
__global__ void build_inv(const int* __restrict__ ids, int* __restrict__ inv,
                          int npages, int nslots) {
  const int i = threadIdx.x;
  if (i < npages) inv[i] = -1;
  __syncthreads();
  if (i < nslots) inv[ids[i]] = i;
}

__global__ void page_fill(const float* __restrict__ kg, const float* __restrict__ vg,
                          const float* __restrict__ cache_in, const int* __restrict__ inv,
                          float* __restrict__ cache) {
  const int page = blockIdx.x, half = blockIdx.y;
  const int slot = inv[page];
  float4* d4 = (float4*)cache;
  const size_t dbase = (((size_t)page * 2 + half) * 8) * 1024;
  if (slot >= 0) {
    const int b = slot >> 6, blk = slot & 63;
    const float4* s4 = (const float4*)(half ? vg : kg);
    for (int f = threadIdx.x; f < 8192; f += blockDim.x) {
      const int d = f & 31, s = (f >> 5) & 31, h = f >> 10;
      d4[dbase + (size_t)h * 1024 + s * 32 + d] =
          s4[(((size_t)b * SS + blk * 32 + s) * 8 + h) * 32 + d];
    }
  } else {
    const float4* s4 = (const float4*)cache_in;
    for (int f = threadIdx.x; f < 8192; f += blockDim.x)
      d4[dbase + f] = s4[dbase + f];
  }
}

__global__ void cache_copy(const float* __restrict__ src, float* __restrict__ dst, int n4) {
  const float4* s = (const float4*)src;
  float4* d = (float4*)dst;
  for (int i = blockIdx.x * blockDim.x + threadIdx.x; i < n4; i += gridDim.x * blockDim.x)
    d[i] = s[i];
}
__global__ void cache_scatter(const float* __restrict__ kg, const float* __restrict__ vg,
                              const int* __restrict__ ids, float* __restrict__ cache) {
  const int slot = blockIdx.x;
  const int half = blockIdx.y;
  const int b = slot >> 6, blk = slot & 63;
  const int page = ids[slot];
  const float4* s4 = (const float4*)(half ? vg : kg);
  float4* d4 = (float4*)cache;
  for (int f = threadIdx.x; f < 8192; f += blockDim.x) {
    const int d = f & 31, s = (f >> 5) & 31, h = f >> 10;
    d4[(((size_t)page * 2 + half) * 8 + h) * 1024 + s * 32 + d] =
        s4[(((size_t)b * SS + blk * 32 + s) * 8 + h) * 32 + d];
  }
}

extern "C" void kernel_launch(void* const* d_in, const int* in_sizes, int n_in,
                              void* d_out, int out_size, void* d_ws, size_t ws_size,
                              hipStream_t stream) {
  const float* q = (const float*)d_in[0];
  const float* k = (const float*)d_in[1];
  const float* v = (const float*)d_in[2];
  const float* cache_in = (const float*)d_in[3];
  const int* ids = (const int*)d_in[4];
  const float* sink = (const float*)d_in[5];
  float* out = (float*)d_out;
  float* cache_out = out + (size_t)BB * SS * HQ * DD;

  const int nslots = in_sizes[4];                       // 128
  const int npages = in_sizes[3] / (2 * HKV * 32 * DD); // 128

  const size_t kvBytes = (size_t)BB * HKV * SS * DD * 2; // 8,388,608 each
  const size_t need = 4096 + 2 * kvBytes;
  const bool smallMaps = (npages <= 1024) && (nslots <= 1024);

  if (ws_size >= need && smallMaps) {
    int* inv = (int*)d_ws;
    unsigned short* kbp = (unsigned short*)((char*)d_ws + 4096);
    unsigned short* vtp = kbp + kvBytes / 2;
    build_inv<<<1, 1024, 0, stream>>>(ids, inv, npages, nslots);
    page_fill<<<dim3(npages, 2), 256, 0, stream>>>(k, v, cache_in, inv, cache_out);
    prep_kv<<<dim3(BB * HKV * 32, 2), 256, 0, stream>>>(k, v, kbp, vtp);
    attn_kernel<<<512, 512, 0, stream>>>(q, sink, out, kbp, vtp);
  } else if (ws_size >= (size_t)npages * sizeof(int) && smallMaps) {
    int* inv = (int*)d_ws;
    build_inv<<<1, 1024, 0, stream>>>(ids, inv, npages, nslots);
    page_fill<<<dim3(npages, 2), 256, 0, stream>>>(k, v, cache_in, inv, cache_out);
    attn_fallback<<<512, 512, 0, stream>>>(q, k, v, sink, out);
  } else {
    cache_copy<<<4096, 256, 0, stream>>>(cache_in, cache_out, (BB * SS * HKV * DD * 2) / 4);
    cache_scatter<<<dim3(BB * 64, 2), 256, 0, stream>>>(k, v, ids, cache_out);
    attn_fallback<<<512, 512, 0, stream>>>(q, k, v, sink, out);
  }
}